// Round 1
// baseline (291.375 us; speedup 1.0000x reference)
//
#include <hip/hip_runtime.h>

// Holonomy: for each (b, n) chain, hol = M_15 @ ... @ M_0, M_t = Gamma[b, loops[n][t+1], loops[n][t]]
// Gamma: [4, 512, 512, 8, 8] fp32 (each 8x8 matrix is a contiguous 64-float block)
// loops: [64, 17] int
// out:   [4, 64, 8, 8] fp32
//
// Mapping: one wave per chain, one wave per block (256 blocks x 64 threads) so the
// loop indices are compiler-provably wave-uniform (scalar loads). Lane = r*8+c holds
// element (r,c) of every matrix. All 16 gathered matrices prefetched with coalesced
// 256B loads.
//
// This version: the 16-step serial left-fold (hol = M_t @ hol) is replaced by a
// balanced product tree: 8 independent pair-products -> 4 -> 2 -> 1. Matrix product
// is associative, so M15@...@M0 = ((M15@M14)@(M13@M12))@... . Critical path shrinks
// from 16 dependent matmuls to 4, and level-1's 8 independent matmuls both hide the
// ds_bpermute latency and overlap with the still-in-flight global loads (each p[i]
// only needs vmcnt coverage of its own two matrices).

#define BATCH    4
#define NLOOPS   64
#define SEQ      512
#define LOOPLEN  17
#define NSTEPS   (LOOPLEN - 1)   // 16

// C = A @ B on 8x8 matrices distributed one element per lane (lane = r*8+c).
// rbase = lane & 56 (start of this lane's row group), c = lane & 7.
// Two accumulator chains halve the dependent-FMA latency.
__device__ __forceinline__ float mat8_mul(float A, float B, int rbase, int c)
{
    float acc0 = 0.0f, acc1 = 0.0f;
#pragma unroll
    for (int k = 0; k < 8; k += 2) {
        const float a0 = __shfl(A, rbase + k,       64);  // A[r][k]
        const float b0 = __shfl(B, k * 8 + c,       64);  // B[k][c]
        const float a1 = __shfl(A, rbase + k + 1,   64);
        const float b1 = __shfl(B, (k + 1) * 8 + c, 64);
        acc0 = fmaf(a0, b0, acc0);
        acc1 = fmaf(a1, b1, acc1);
    }
    return acc0 + acc1;
}

__global__ __launch_bounds__(64) void holonomy_kernel(
    const float* __restrict__ Gamma,
    const int*   __restrict__ loops,
    float*       __restrict__ out)
{
    const int lane  = threadIdx.x;        // 0..63
    const int chain = blockIdx.x;         // 0..255
    const int b = chain >> 6;             // chain / NLOOPS
    const int n = chain & 63;             // chain % NLOOPS  (block-uniform -> scalar)
    const int rbase = lane & 56;
    const int c     = lane & 7;

    const int* lp = loops + n * LOOPLEN;

    // Prefetch all 16 matrices: independent loads, waits folded into tree level 1.
    // Gamma[b, i, j, :, :] contiguous: offset = ((b*SEQ + i)*SEQ + j)*64
    float m[NSTEPS];
    const int base_b = b * SEQ * SEQ * 64;
#pragma unroll
    for (int t = 0; t < NSTEPS; ++t) {
        const int j = lp[t];
        const int i = lp[t + 1];
        m[t] = Gamma[base_b + (i * SEQ + j) * 64 + lane];
    }

    // Balanced product tree; product order is descending index (left-multiply fold).
    // Level 1: 8 independent products p[i] = M_{2i+1} @ M_{2i}
    float p[8];
#pragma unroll
    for (int i = 0; i < 8; ++i)
        p[i] = mat8_mul(m[2 * i + 1], m[2 * i], rbase, c);

    // Level 2: q[i] = p_{2i+1} @ p_{2i}
    float q[4];
#pragma unroll
    for (int i = 0; i < 4; ++i)
        q[i] = mat8_mul(p[2 * i + 1], p[2 * i], rbase, c);

    // Level 3: s[i] = q_{2i+1} @ q_{2i}
    float s[2];
#pragma unroll
    for (int i = 0; i < 2; ++i)
        s[i] = mat8_mul(q[2 * i + 1], q[2 * i], rbase, c);

    // Level 4: hol = s1 @ s0 = M15 @ ... @ M0
    const float hol = mat8_mul(s[1], s[0], rbase, c);

    out[chain * 64 + lane] = hol;
}

extern "C" void kernel_launch(void* const* d_in, const int* in_sizes, int n_in,
                              void* d_out, int out_size, void* d_ws, size_t ws_size,
                              hipStream_t stream) {
    const float* Gamma = (const float*)d_in[0];
    const int*   loops = (const int*)d_in[1];
    float*       out   = (float*)d_out;

    // 256 chains, one wave each, one wave per block -> spread across all 256 CUs
    dim3 grid(BATCH * NLOOPS), block(64);
    holonomy_kernel<<<grid, block, 0, stream>>>(Gamma, loops, out);
}